// Round 4
// baseline (38.978 us; speedup 1.0000x reference)
//
#include <hip/hip_runtime.h>

#define RW 25            // floats per row: K + 24 LSP frequencies
#define RPB 128          // rows per block (== threads per block)

typedef float f4 __attribute__((ext_vector_type(4)));
typedef float f2 __attribute__((ext_vector_type(2)));

__global__ __launch_bounds__(128) void lsp2lpc_kernel(const float* __restrict__ in,
                                                      float* __restrict__ out) {
    __shared__ float sm[RPB * RW];   // 12.8 KB -> 12 blocks/CU (24 waves/CU)
    const long long row0 = (long long)blockIdx.x * RPB;
    const f4* gin4  = (const f4*)(in  + row0 * RW);
    f4*       gout4 = (f4*)(out + row0 * RW);
    f4*       sm4   = (f4*)sm;
    const int tid = threadIdx.x;

    // coalesced vectorized global->LDS staging: 800 float4 = 6*128 + 32
    #pragma unroll
    for (int i = 0; i < 6; ++i)
        sm4[tid + i * 128] = gin4[tid + i * 128];
    if (tid < 32)
        sm4[tid + 768] = gin4[tid + 768];
    __syncthreads();

    // each thread owns one row in LDS (stride 25: conflict-free, gcd(25,32)=1)
    const float* wr = &sm[tid * RW];
    const float K = wr[0];

    // Hoist all 12 packed coefficient pairs: c[k] = (-2cos w_p, -2cos w_q)
    // p roots come from wf[1::2] = w[2],w[4],..,w[24]; q from wf[0::2] = w[1],..,w[23]
    f2 c[12];
    #pragma unroll
    for (int k = 0; k < 12; ++k) {
        c[k].x = -2.f * __cosf(wr[2 + 2 * k]);
        c[k].y = -2.f * __cosf(wr[1 + 2 * k]);
    }

    // (P[j],Q[j]) packed as float2 -> v_pk_fma_f32.
    // Monic polys in descending powers; leading coeff at index 0.
    f2 PQ[RW];
    #pragma unroll
    for (int j = 0; j < RW; ++j) PQ[j] = (f2)(0.f);
    PQ[0] = (f2)(1.f);

    // multiply in one conjugate-pair quadratic (x^2 + a x + 1) at a time:
    //   new[j] = old[j] + a*old[j-1] + old[j-2], j descending (in place).
    #pragma unroll
    for (int k = 0; k < 12; ++k) {
        const f2 a = c[k];
        #pragma unroll
        for (int j = 2 * k + 2; j >= 2; --j)
            PQ[j] = PQ[j] + a * PQ[j - 1] + PQ[j - 2];
        PQ[1] = PQ[1] + a * PQ[0];
    }

    // epilogue: a[i] = 0.5*((P[i+1]-P[i]) + (Q[i+1]+Q[i])) ; out row = [K, a]
    // own-row write after own-row reads -> no barrier needed here
    float* orow = &sm[tid * RW];
    orow[0] = K;
    #pragma unroll
    for (int i = 0; i < 24; ++i)
        orow[1 + i] = 0.5f * ((PQ[i + 1].x - PQ[i].x) + (PQ[i + 1].y + PQ[i].y));
    __syncthreads();

    // coalesced vectorized LDS->global (plain stores: let L3 absorb the
    // output stream — in+out working set = 210 MB < 256 MB L3)
    #pragma unroll
    for (int i = 0; i < 6; ++i)
        gout4[tid + i * 128] = sm4[tid + i * 128];
    if (tid < 32)
        gout4[tid + 768] = sm4[tid + 768];
}

extern "C" void kernel_launch(void* const* d_in, const int* in_sizes, int n_in,
                              void* d_out, int out_size, void* d_ws, size_t ws_size,
                              hipStream_t stream) {
    const float* in = (const float*)d_in[0];
    float* out = (float*)d_out;
    const int nrows = in_sizes[0] / RW;          // 16*65536 = 1,048,576
    const int nblocks = nrows / RPB;             // 8192 (exactly divisible)
    lsp2lpc_kernel<<<nblocks, RPB, 0, stream>>>(in, out);
}

// Round 5
// 38.153 us; speedup vs baseline: 1.0216x; 1.0216x over previous
//
#include <hip/hip_runtime.h>

#define RW 25            // floats per row: K + 24 LSP frequencies
#define RPB 256          // rows per tile (== threads per block)
#define TPB 4            // tiles per block (1024 blocks * 4 = 4096 tiles)

typedef float f4 __attribute__((ext_vector_type(4)));
typedef float f2 __attribute__((ext_vector_type(2)));

__global__ __launch_bounds__(256, 4) void lsp2lpc_kernel(const float* __restrict__ in,
                                                         float* __restrict__ out) {
    __shared__ float sm[RPB * RW];   // 25.6 KB; 4 blocks/CU (VGPR-capped)
    f4* sm4 = (f4*)sm;
    const int tid = threadIdx.x;
    const long long tile0 = (long long)blockIdx.x * TPB;   // chunked: contiguous 400 KB/block

    // prologue: cold prefetch of tile 0 into registers (7 x float4)
    f4 r0, r1, r2, r3, r4, r5, r6;
    {
        const f4* g = (const f4*)(in + tile0 * (RPB * RW));
        r0 = g[tid];        r1 = g[tid + 256];  r2 = g[tid + 512];
        r3 = g[tid + 768];  r4 = g[tid + 1024]; r5 = g[tid + 1280];
        if (tid < 64) r6 = g[tid + 1536];
    }

    for (int t = 0; t < TPB; ++t) {
        // stage tile t: regs -> LDS (regs dead afterwards, reused by prefetch)
        sm4[tid] = r0;        sm4[tid + 256] = r1;  sm4[tid + 512] = r2;
        sm4[tid + 768] = r3;  sm4[tid + 1024] = r4; sm4[tid + 1280] = r5;
        if (tid < 64) sm4[tid + 1536] = r6;
        __syncthreads();

        // prefetch tile t+1 NOW — its ~900cy HBM latency hides under the
        // compute phase below; the drain happens at the post-compute barrier.
        if (t + 1 < TPB) {
            const f4* g = (const f4*)(in + (tile0 + t + 1) * (RPB * RW));
            r0 = g[tid];        r1 = g[tid + 256];  r2 = g[tid + 512];
            r3 = g[tid + 768];  r4 = g[tid + 1024]; r5 = g[tid + 1280];
            if (tid < 64) r6 = g[tid + 1536];
        }

        // ---- compute: each thread owns one LDS row (stride 25, conflict-free) ----
        const float* wr = &sm[tid * RW];
        const float K = wr[0];

        // packed coefficient pairs: c[k] = (-2cos w_p, -2cos w_q)
        f2 c[12];
        #pragma unroll
        for (int k = 0; k < 12; ++k) {
            c[k].x = -2.f * __cosf(wr[2 + 2 * k]);
            c[k].y = -2.f * __cosf(wr[1 + 2 * k]);
        }

        // (P,Q) packed as float2 -> v_pk_fma_f32
        f2 PQ[RW];
        #pragma unroll
        for (int j = 0; j < RW; ++j) PQ[j] = (f2)(0.f);
        PQ[0] = (f2)(1.f);

        #pragma unroll
        for (int k = 0; k < 12; ++k) {
            const f2 a = c[k];
            #pragma unroll
            for (int j = 2 * k + 2; j >= 2; --j)
                PQ[j] = PQ[j] + a * PQ[j - 1] + PQ[j - 2];
            PQ[1] = PQ[1] + a * PQ[0];
        }

        // epilogue into own LDS row (no cross-thread hazard -> no barrier here)
        float* orow = &sm[tid * RW];
        orow[0] = K;
        #pragma unroll
        for (int i = 0; i < 24; ++i)
            orow[1 + i] = 0.5f * ((PQ[i + 1].x - PQ[i].x) + (PQ[i + 1].y + PQ[i].y));
        __syncthreads();   // epilogue visible; prefetch drained (already covered)

        // coalesced vectorized LDS -> global store of tile t
        f4* go = (f4*)(out + (tile0 + t) * (RPB * RW));
        go[tid] = sm4[tid];               go[tid + 256] = sm4[tid + 256];
        go[tid + 512] = sm4[tid + 512];   go[tid + 768] = sm4[tid + 768];
        go[tid + 1024] = sm4[tid + 1024]; go[tid + 1280] = sm4[tid + 1280];
        if (tid < 64) go[tid + 1536] = sm4[tid + 1536];
        __syncthreads();   // store-phase LDS reads done -> buffer free for next stage
    }
}

extern "C" void kernel_launch(void* const* d_in, const int* in_sizes, int n_in,
                              void* d_out, int out_size, void* d_ws, size_t ws_size,
                              hipStream_t stream) {
    const float* in = (const float*)d_in[0];
    float* out = (float*)d_out;
    const int nrows = in_sizes[0] / RW;              // 1,048,576
    const int nblocks = nrows / (RPB * TPB);         // 1024 (exact)
    lsp2lpc_kernel<<<nblocks, RPB, 0, stream>>>(in, out);
}